// Round 3
// baseline (1364.918 us; speedup 1.0000x reference)
//
#include <hip/hip_runtime.h>
#include <cstdint>
#include <cstddef>

#define D 128
#define NBINS 4096      // top-12-bit histogram of monotonic key
#define CAND_CAP 32768
#define SEL_CAP  32768
#define TIE_CAP  4096

// ---- monotonic float<->uint key (increasing key == increasing float) ----
__device__ __forceinline__ uint32_t f2key(float f) {
    uint32_t u = __float_as_uint(f);
    return (u & 0x80000000u) ? ~u : (u | 0x80000000u);
}
__device__ __forceinline__ float key2f(uint32_t k) {
    uint32_t u = (k & 0x80000000u) ? (k ^ 0x80000000u) : ~k;
    return __uint_as_float(u);
}

// misc layout (uint32 words): [0]=cand count, [1]=prefix lower bound,
// [2]=n selected, [4]=inv_len (as float bits)

// ---------------- kernel 1: init + 1/||v|| ----------------
__global__ void k_init(const float* __restrict__ v, float* __restrict__ out,
                       uint32_t* __restrict__ hist, uint32_t* __restrict__ misc) {
    __shared__ float red[256];
    int t = threadIdx.x;
    for (int i = t; i < NBINS; i += 256) hist[i] = 0u;
    if (t < 64) misc[t] = 0u;
    if (t < D)  out[t]  = 0.f;
    float s = (t < D) ? v[t] * v[t] : 0.f;
    red[t] = s;
    __syncthreads();
    for (int w = 128; w > 0; w >>= 1) {
        if (t < w) red[t] += red[t + w];
        __syncthreads();
    }
    if (t == 0) {
        float len = sqrtf(red[0]);
        ((float*)misc)[4] = 1.0f / len;
    }
}

// ---------------- kernel 2: scores + keys + histogram (the heavy one) ----------------
// One wave handles 2 rows per loop step (64 lanes x float4 = 1KB = 2 rows),
// unrolled x2 (two independent dwordx4 loads in flight per lane).
// Chunked wave partition: contiguous streaming + contiguous 8B key writes.
__global__ __launch_bounds__(256) void k_scores(
        const float4* __restrict__ x4, const float* __restrict__ v,
        const uint32_t* __restrict__ misc, uint32_t* __restrict__ keys,
        uint32_t* __restrict__ ghist, int nrows) {
    __shared__ uint32_t lh[NBINS];
    for (int i = threadIdx.x; i < NBINS; i += blockDim.x) lh[i] = 0u;
    __syncthreads();

    float inv_len = ((const float*)misc)[4];
    int lane = threadIdx.x & 63;
    int l32  = lane & 31;
    int half = lane >> 5;                 // 0 or 1: which row of the pair
    float4 vf = reinterpret_cast<const float4*>(v)[l32];

    long wave = (long)((blockIdx.x * blockDim.x + threadIdx.x) >> 6);
    long nw   = (long)((gridDim.x * blockDim.x) >> 6);
    long npairs = ((long)nrows + 1) >> 1;
    long per = (npairs + nw - 1) / nw;
    long p0 = wave * per;
    long p1 = p0 + per; if (p1 > npairs) p1 = npairs;

    long p = p0;
    for (; p + 2 <= p1; p += 2) {
        int rowA = (int)(2 * p) + half;          // always < nrows (full pairs)
        int rowB = rowA + 2;
        bool okB = rowB < nrows;
        float4 xa = x4[(size_t)rowA * (D / 4) + l32];
        float4 xb = okB ? x4[(size_t)rowB * (D / 4) + l32]
                        : make_float4(0.f, 0.f, 0.f, 0.f);
        float sa = xa.x * vf.x + xa.y * vf.y + xa.z * vf.z + xa.w * vf.w;
        float sb = xb.x * vf.x + xb.y * vf.y + xb.z * vf.z + xb.w * vf.w;
        sa += __shfl_xor(sa, 1);  sb += __shfl_xor(sb, 1);
        sa += __shfl_xor(sa, 2);  sb += __shfl_xor(sb, 2);
        sa += __shfl_xor(sa, 4);  sb += __shfl_xor(sb, 4);
        sa += __shfl_xor(sa, 8);  sb += __shfl_xor(sb, 8);
        sa += __shfl_xor(sa, 16); sb += __shfl_xor(sb, 16);
        if (l32 == 0) {
            uint32_t ka = f2key(sa * inv_len);
            keys[rowA] = ka;
            atomicAdd(&lh[ka >> 20], 1u);
            if (okB) {
                uint32_t kb = f2key(sb * inv_len);
                keys[rowB] = kb;
                atomicAdd(&lh[kb >> 20], 1u);
            }
        }
    }
    for (; p < p1; ++p) {
        int row = (int)(2 * p) + half;
        float s = 0.f;
        if (row < nrows) {
            float4 xv = x4[(size_t)row * (D / 4) + l32];
            s = xv.x * vf.x + xv.y * vf.y + xv.z * vf.z + xv.w * vf.w;
        }
        s += __shfl_xor(s, 1);
        s += __shfl_xor(s, 2);
        s += __shfl_xor(s, 4);
        s += __shfl_xor(s, 8);
        s += __shfl_xor(s, 16);
        if (l32 == 0 && row < nrows) {
            uint32_t k = f2key(s * inv_len);
            keys[row] = k;
            atomicAdd(&lh[k >> 20], 1u);
        }
    }
    __syncthreads();
    for (int i = threadIdx.x; i < NBINS; i += blockDim.x) {
        uint32_t c = lh[i];
        if (c) atomicAdd(&ghist[i], c);
    }
}

// ---------------- kernel 3: find threshold bin (single block) ----------------
__global__ void k_findbin(const uint32_t* __restrict__ ghist,
                          const int* __restrict__ kin,
                          uint32_t* __restrict__ misc, int nrows) {
    __shared__ uint32_t chunk[256];
    __shared__ uint32_t h[NBINS];
    int t = threadIdx.x;
    uint32_t local = 0;
    for (int i = 0; i < 16; ++i) {
        uint32_t c = ghist[t * 16 + i];
        h[t * 16 + i] = c;
        local += c;
    }
    chunk[t] = local;
    __syncthreads();
    if (t == 0) {
        long kk = kin[0]; if (kk > nrows) kk = nrows; if (kk < 1) kk = 1;
        long cum = 0; int b = 0;
        for (int c = 255; c >= 0; --c) {
            if (cum + (long)chunk[c] >= kk) {
                for (int i = 15; i >= 0; --i) {
                    int bin = c * 16 + i;
                    cum += (long)h[bin];
                    if (cum >= kk) { b = bin; break; }
                }
                break;
            }
            cum += (long)chunk[c];
        }
        misc[1] = (uint32_t)b << 20;  // lower bound of threshold bin
    }
}

// ---------------- kernel 4: compact candidates >= bin lower bound ----------------
// Expected candidate count for N(0,1) scores, k=2048: ~2.7K (bin width = 1/8
// binade near y~3.0). CAND_CAP=32768 gives >10x margin.
__global__ void k_compact(const uint32_t* __restrict__ keys,
                          uint32_t* __restrict__ misc,
                          uint32_t* __restrict__ candk, uint32_t* __restrict__ candi,
                          int nrows) {
    uint32_t lo = misc[1];
    uint32_t* gcount = &misc[0];
    int tid = blockIdx.x * blockDim.x + threadIdx.x;
    int stride = gridDim.x * blockDim.x;
    int n4 = nrows >> 2;
    const uint4* k4 = reinterpret_cast<const uint4*>(keys);
    for (int i = tid; i < n4; i += stride) {
        uint4 kv = k4[i];
        uint32_t base = 4u * (uint32_t)i;
        if (kv.x >= lo) { uint32_t p = atomicAdd(gcount, 1u); if (p < CAND_CAP) { candk[p] = kv.x; candi[p] = base + 0u; } }
        if (kv.y >= lo) { uint32_t p = atomicAdd(gcount, 1u); if (p < CAND_CAP) { candk[p] = kv.y; candi[p] = base + 1u; } }
        if (kv.z >= lo) { uint32_t p = atomicAdd(gcount, 1u); if (p < CAND_CAP) { candk[p] = kv.z; candi[p] = base + 2u; } }
        if (kv.w >= lo) { uint32_t p = atomicAdd(gcount, 1u); if (p < CAND_CAP) { candk[p] = kv.w; candi[p] = base + 3u; } }
    }
    for (int i = (n4 << 2) + tid; i < nrows; i += stride) {
        uint32_t kv = keys[i];
        if (kv >= lo) { uint32_t p = atomicAdd(gcount, 1u); if (p < CAND_CAP) { candk[p] = kv; candi[p] = (uint32_t)i; } }
    }
}

// ---------------- kernel 5: exact radix top-k among candidates (single block) ----------------
__global__ __launch_bounds__(1024) void k_select(
        uint32_t* __restrict__ misc,
        const uint32_t* __restrict__ candk, const uint32_t* __restrict__ candi,
        const int* __restrict__ kin,
        uint32_t* __restrict__ seli, float* __restrict__ selg, int nrows) {
    __shared__ uint32_t hist[256];
    __shared__ uint32_t tie[TIE_CAP];
    __shared__ uint32_t sh_prefix, sh_r, nsel, ntie;
    int t = threadIdx.x;
    int ncand = (int)min(misc[0], (uint32_t)CAND_CAP);
    int kk = kin[0];
    if (kk > nrows) kk = nrows;
    if (kk > SEL_CAP) kk = SEL_CAP;
    if (kk > ncand) kk = ncand;
    if (kk < 0) kk = 0;
    if (t == 0) { sh_prefix = 0u; sh_r = (uint32_t)kk; nsel = 0u; ntie = 0u; }
    __syncthreads();
    if (kk == 0) { if (t == 0) misc[2] = 0u; return; }

    uint32_t mask = 0u;
    for (int shift = 24; shift >= 0; shift -= 8) {
        if (t < 256) hist[t] = 0u;
        __syncthreads();
        uint32_t prefix = sh_prefix;
        for (int i = t; i < ncand; i += blockDim.x) {
            uint32_t key = candk[i];
            if ((key & mask) == prefix) atomicAdd(&hist[(key >> shift) & 0xffu], 1u);
        }
        __syncthreads();
        if (t == 0) {
            uint32_t r = sh_r, cum = 0u;
            int d = 255;
            for (; d >= 0; --d) {
                if (cum + hist[d] >= r) break;
                cum += hist[d];
            }
            if (d < 0) d = 0;
            sh_r = r - cum;
            sh_prefix = prefix | ((uint32_t)d << shift);
        }
        __syncthreads();
        mask |= (0xffu << shift);
    }
    uint32_t tkey = sh_prefix;
    uint32_t need = sh_r;  // how many of the tied (== tkey) elements to take

    for (int i = t; i < ncand; i += blockDim.x) {
        uint32_t key = candk[i];
        if (key > tkey) {
            uint32_t p = atomicAdd(&nsel, 1u);
            if (p < SEL_CAP) {
                seli[p] = candi[i];
                float y = key2f(key);
                selg[p] = 1.f / (1.f + expf(-y));
            }
        } else if (key == tkey) {
            uint32_t p = atomicAdd(&ntie, 1u);
            if (p < TIE_CAP) tie[p] = candi[i];
        }
    }
    __syncthreads();
    uint32_t nt = min(ntie, (uint32_t)TIE_CAP);
    if (need > nt) need = nt;  // overflow guard
    float gt = 1.f / (1.f + expf(-key2f(tkey)));
    for (uint32_t i = t; i < nt; i += blockDim.x) {
        uint32_t my = tie[i];
        uint32_t rank = 0;
        for (uint32_t j = 0; j < nt; ++j) rank += (tie[j] < my) ? 1u : 0u;
        if (rank < need) {  // ties broken by smallest index, like lax.top_k
            uint32_t p = atomicAdd(&nsel, 1u);
            if (p < SEL_CAP) { seli[p] = my; selg[p] = gt; }
        }
    }
    __syncthreads();
    if (t == 0) misc[2] = min(nsel, (uint32_t)SEL_CAP);
}

// ---------------- kernel 6: gather + weighted sum ----------------
__global__ __launch_bounds__(256) void k_accum(
        const float4* __restrict__ x4, const uint32_t* __restrict__ misc,
        const uint32_t* __restrict__ seli, const float* __restrict__ selg,
        float* __restrict__ out) {
    __shared__ float part[D];
    int t = threadIdx.x;
    if (t < D) part[t] = 0.f;
    __syncthreads();
    int nsel = (int)misc[2];
    int l32 = t & 31;              // lane within 32-lane group (one row / group / iter)
    int grp = t >> 5;              // 8 groups per 256-thread block
    int g = blockIdx.x * (blockDim.x >> 5) + grp;
    int ngrp = (gridDim.x * blockDim.x) >> 5;
    float4 acc = make_float4(0.f, 0.f, 0.f, 0.f);
    for (int e = g; e < nsel; e += ngrp) {
        uint32_t row = seli[e];
        float gate = selg[e];
        float4 xv = x4[(size_t)row * (D / 4) + l32];
        acc.x += gate * xv.x; acc.y += gate * xv.y;
        acc.z += gate * xv.z; acc.w += gate * xv.w;
    }
    atomicAdd(&part[l32 * 4 + 0], acc.x);
    atomicAdd(&part[l32 * 4 + 1], acc.y);
    atomicAdd(&part[l32 * 4 + 2], acc.z);
    atomicAdd(&part[l32 * 4 + 3], acc.w);
    __syncthreads();
    if (t < D) atomicAdd(&out[t], part[t]);
}

extern "C" void kernel_launch(void* const* d_in, const int* in_sizes, int n_in,
                              void* d_out, int out_size, void* d_ws, size_t ws_size,
                              hipStream_t stream) {
    const float* x = (const float*)d_in[0];
    const float* v = (const float*)d_in[1];
    const int* kin = (const int*)d_in[2];
    float* out = (float*)d_out;
    int nrows = in_sizes[0] / D;

    char* ws = (char*)d_ws;
    size_t off = 0;
    uint32_t* keys = (uint32_t*)(ws + off); off += (size_t)nrows * 4;
    off = (off + 255) & ~(size_t)255;
    uint32_t* hist = (uint32_t*)(ws + off); off += NBINS * 4;
    uint32_t* misc = (uint32_t*)(ws + off); off += 256;
    uint32_t* candk = (uint32_t*)(ws + off); off += CAND_CAP * 4;
    uint32_t* candi = (uint32_t*)(ws + off); off += CAND_CAP * 4;
    uint32_t* seli = (uint32_t*)(ws + off); off += SEL_CAP * 4;
    float* selg = (float*)(ws + off); off += SEL_CAP * 4;
    (void)ws_size; (void)x; (void)out_size; (void)n_in;

    const float4* x4 = (const float4*)x;

    k_init<<<1, 256, 0, stream>>>(v, out, hist, misc);
    k_scores<<<2048, 256, 0, stream>>>(x4, v, misc, keys, hist, nrows);
    k_findbin<<<1, 256, 0, stream>>>(hist, kin, misc, nrows);
    k_compact<<<512, 256, 0, stream>>>(keys, misc, candk, candi, nrows);
    k_select<<<1, 1024, 0, stream>>>(misc, candk, candi, kin, seli, selg, nrows);
    k_accum<<<64, 256, 0, stream>>>(x4, misc, seli, selg, out);
}